// Round 10
// baseline (112.964 us; speedup 1.0000x reference)
//
#include <hip/hip_runtime.h>
#include <cstdint>
#include <cstddef>

#define N_SEQ 4096
#define D_HEAD 128
#define KP_DIM 256

typedef __attribute__((ext_vector_type(4))) float f32x4;
typedef __attribute__((ext_vector_type(8))) short bf16x8;
typedef __attribute__((ext_vector_type(4))) short s16x4;
typedef __attribute__((ext_vector_type(2))) unsigned int u32x2;

static __device__ __forceinline__ short f2bf(float f) {
  uint32_t u = __builtin_bit_cast(uint32_t, f);
  u += 0x7FFFu + ((u >> 16) & 1u);
  return (short)(u >> 16);
}

static __device__ __forceinline__ unsigned int cvtpk(float a, float b) {
  unsigned int r;
  asm("v_cvt_pk_bf16_f32 %0, %1, %2" : "=v"(r) : "v"(a), "v"(b));
  return r;
}

static __device__ __forceinline__ int swz8(int r) { return (r ^ (r >> 2)) & 7; }

// ---------------------------------------------------------------------------
// Stage 0: convert E_W,F_W f32 -> bf16 wbf[2][256][4096] (d_out scratch)
// ---------------------------------------------------------------------------
__global__ __launch_bounds__(256) void conv_w_kernel(
    const float* __restrict__ EW, const float* __restrict__ FW,
    short* __restrict__ wbf) {
  const int idx = blockIdx.x * 256 + threadIdx.x;
  const int half = 262144;
  f32x4 v = (idx < half) ? *(const f32x4*)(EW + (size_t)idx * 4)
                         : *(const f32x4*)(FW + (size_t)(idx - half) * 4);
  u32x2 h = {cvtpk(v[0], v[1]), cvtpk(v[2], v[3])};
  *(u32x2*)(wbf + (size_t)idx * 4) = h;
}

// ---------------------------------------------------------------------------
// Stage 1: FULL-K projection, no partials, no reduce. grid 512 (XCD-chunked),
// 256 thr = 4 waves (2k x 2d of 32x32). Block = (b, p, kq, dh): output tile
// k in [kq*64,+64), d in [dh*64,+64), K = all 4096 n in 64 steps of BK=64.
// Full f32 register accumulation; bias fused in epilogue; p=1 writes
// vpt[d][k] via swapped-operand MFMA (verified in R4). W staged via
// global_load_lds from bf16 wbf (pre-swizzled source); X reg-transposed
// + cvt_pk. X loads issued first, W second: vmcnt(2) frees X convert,
// vmcnt(0) only just before the barrier.
// ---------------------------------------------------------------------------
__global__ __launch_bounds__(256, 4) void proj_full_kernel(
    const float* __restrict__ Kin, const float* __restrict__ Vin,
    const short* __restrict__ wbf, const float* __restrict__ Eb,
    const float* __restrict__ Fb, short* __restrict__ kp,
    short* __restrict__ vpt) {
  const int bid = blockIdx.x;                 // 0..511
  const int wk = (bid & 7) * 64 + (bid >> 3); // XCD x owns wk [64x, 64x+64)
  const int kq = wk & 3;                      // 4 k-quarter blocks adjacent ->
  const int dh = (wk >> 2) & 1;               //   co-XCD X-slice reuse
  const int b  = (wk >> 3) & 31;
  const int p  = (wk >> 8) & 1;               // XCDs 0-3: p=0, 4-7: p=1

  const float* __restrict__ X = (p == 0 ? Kin : Vin) + (size_t)b * (N_SEQ * D_HEAD);
  const short* __restrict__ wp =
      wbf + (size_t)p * (KP_DIM * N_SEQ) + (size_t)(kq * 64) * N_SEQ;

  __shared__ __align__(16) short lw[2][64 * 64];  // 8KB x2: W tile [64 k][64 n]
  __shared__ __align__(16) short xt[2][64 * 64];  // 8KB x2: X^T tile [64 d][64 n]

  const int t = threadIdx.x;
  const int lane = t & 63;
  const int w = t >> 6;            // 0..3
  const int wkk = (w >> 1) * 32;   // wave k offset in tile
  const int wdd = (w & 1) * 32;    // wave d offset in tile
  const int l15 = lane & 15;
  const int l4 = lane >> 4;
  const int dq = t & 15;           // d-quad for X staging (0..15)
  const int ng = t >> 4;           // n-group (0..15) for X staging

  f32x4 acc[2][2];
#pragma unroll
  for (int i = 0; i < 2; ++i)
#pragma unroll
    for (int j = 0; j < 2; ++j) acc[i][j] = (f32x4){0.f, 0.f, 0.f, 0.f};

  f32x4 xreg[4];

  // ---- prologue: stage iter 0 (X loads first, then W gload_lds) ----
#pragma unroll
  for (int i = 0; i < 4; ++i)
    xreg[i] = *(const f32x4*)(X + (size_t)(ng * 4 + i) * D_HEAD + dh * 64 + dq * 4);
#pragma unroll
  for (int i = 0; i < 2; ++i) {
    int g = t + i * 256;           // 16B chunk id 0..511
    int row = g >> 3, c = g & 7;
    __builtin_amdgcn_global_load_lds(
        (const __attribute__((address_space(1))) void*)(wp + (size_t)row * N_SEQ +
                                                        ((c ^ swz8(row)) << 3)),
        (__attribute__((address_space(3))) void*)(&lw[0][g * 8]), 16, 0, 0);
  }
  asm volatile("s_waitcnt vmcnt(2)" ::: "memory");
#pragma unroll
  for (int j = 0; j < 4; ++j) {
    int drow = dq * 4 + j;
    u32x2 hv = {cvtpk(xreg[0][j], xreg[1][j]), cvtpk(xreg[2][j], xreg[3][j])};
    *(u32x2*)(&xt[0][drow * 64 + ((ng * 4) ^ (swz8(drow) << 3))]) = hv;
  }
  asm volatile("s_waitcnt vmcnt(0)" ::: "memory");
  __syncthreads();

  // ---- main loop: 64 iters of BK=64, double-buffered ----
  for (int it = 0; it < 64; ++it) {
    const int cur = it & 1, nxt = cur ^ 1;
    if (it < 63) {
      const int nc = (it + 1) * 64;
#pragma unroll
      for (int i = 0; i < 4; ++i)
        xreg[i] = *(const f32x4*)(X + (size_t)(nc + ng * 4 + i) * D_HEAD + dh * 64 + dq * 4);
#pragma unroll
      for (int i = 0; i < 2; ++i) {
        int g = t + i * 256;
        int row = g >> 3, c = g & 7;
        __builtin_amdgcn_global_load_lds(
            (const __attribute__((address_space(1))) void*)(wp + (size_t)row * N_SEQ + nc +
                                                            ((c ^ swz8(row)) << 3)),
            (__attribute__((address_space(3))) void*)(&lw[nxt][g * 8]), 16, 0, 0);
      }
    }
    // ---- compute on buf[cur] ----
    if (p == 0) {
#pragma unroll
      for (int ks = 0; ks < 2; ++ks) {
        const int col0 = ks * 32 + l4 * 8;
        bf16x8 a[2], bb[2];
#pragma unroll
        for (int mt = 0; mt < 2; ++mt) {
          int row = wkk + mt * 16 + l15;
          a[mt] = *(const bf16x8*)(&lw[cur][row * 64 + (col0 ^ (swz8(row) << 3))]);
        }
#pragma unroll
        for (int nt = 0; nt < 2; ++nt) {
          int row = wdd + nt * 16 + l15;
          bb[nt] = *(const bf16x8*)(&xt[cur][row * 64 + (col0 ^ (swz8(row) << 3))]);
        }
#pragma unroll
        for (int mt = 0; mt < 2; ++mt)
#pragma unroll
          for (int nt = 0; nt < 2; ++nt)
            acc[mt][nt] = __builtin_amdgcn_mfma_f32_16x16x32_bf16(a[mt], bb[nt], acc[mt][nt], 0, 0, 0);
      }
    } else {
#pragma unroll
      for (int ks = 0; ks < 2; ++ks) {
        const int col0 = ks * 32 + l4 * 8;
        bf16x8 a[2], bb[2];
#pragma unroll
        for (int mt = 0; mt < 2; ++mt) {
          int row = wkk + mt * 16 + l15;
          a[mt] = *(const bf16x8*)(&lw[cur][row * 64 + (col0 ^ (swz8(row) << 3))]);
        }
#pragma unroll
        for (int nt = 0; nt < 2; ++nt) {
          int row = wdd + nt * 16 + l15;
          bb[nt] = *(const bf16x8*)(&xt[cur][row * 64 + (col0 ^ (swz8(row) << 3))]);
        }
#pragma unroll
        for (int mt = 0; mt < 2; ++mt)
#pragma unroll
          for (int nt = 0; nt < 2; ++nt)
            acc[mt][nt] = __builtin_amdgcn_mfma_f32_16x16x32_bf16(bb[nt], a[mt], acc[mt][nt], 0, 0, 0);
      }
    }
    if (it < 63) {
      asm volatile("s_waitcnt vmcnt(2)" ::: "memory");  // X landed; W may still fly
#pragma unroll
      for (int j = 0; j < 4; ++j) {
        int drow = dq * 4 + j;
        u32x2 hv = {cvtpk(xreg[0][j], xreg[1][j]), cvtpk(xreg[2][j], xreg[3][j])};
        *(u32x2*)(&xt[nxt][drow * 64 + ((ng * 4) ^ (swz8(drow) << 3))]) = hv;
      }
      asm volatile("s_waitcnt vmcnt(0)" ::: "memory");  // W[nxt] in LDS
    }
    __syncthreads();
  }

  // ---- epilogue: bias + bf16 + direct store ----
  if (p == 0) {
    short* __restrict__ outp = kp + (size_t)b * (KP_DIM * D_HEAD);
#pragma unroll
    for (int mt = 0; mt < 2; ++mt) {
      f32x4 bv = *(const f32x4*)(Eb + kq * 64 + wkk + mt * 16 + l4 * 4);
#pragma unroll
      for (int nt = 0; nt < 2; ++nt)
#pragma unroll
        for (int r = 0; r < 4; ++r) {
          int k = kq * 64 + wkk + mt * 16 + l4 * 4 + r;
          int d = dh * 64 + wdd + nt * 16 + l15;
          outp[(size_t)k * D_HEAD + d] = f2bf(acc[mt][nt][r] + bv[r]);
        }
    }
  } else {
    short* __restrict__ outp = vpt + (size_t)b * (KP_DIM * D_HEAD);
#pragma unroll
    for (int mt = 0; mt < 2; ++mt) {
      float fb = Fb[kq * 64 + wkk + mt * 16 + l15];
#pragma unroll
      for (int nt = 0; nt < 2; ++nt)
#pragma unroll
        for (int r = 0; r < 4; ++r) {
          int d = dh * 64 + wdd + nt * 16 + l4 * 4 + r;  // acc rows = d (swapped)
          int k = kq * 64 + wkk + mt * 16 + l15;
          outp[(size_t)d * KP_DIM + k] = f2bf(acc[mt][nt][r] + fb);
        }
    }
  }
}

// ---------------------------------------------------------------------------
// Stage 2: attention v4 (unchanged from R9 — verified). grid 256, 1024 thr,
// __launch_bounds__(1024,4), 160KB LDS, zero mid-loop barriers.
// ---------------------------------------------------------------------------
__global__ __launch_bounds__(1024, 4) void attn_kernel(
    const float* __restrict__ Q, const short* __restrict__ kp,
    const short* __restrict__ vpt, float* __restrict__ out) {
  const int bid = blockIdx.x;
  const int wk = (bid & 7) * 32 + (bid >> 3);  // XCD-chunked: 4 b's per XCD
  const int b = wk >> 3;
  const int slice = wk & 7;
  const int t = threadIdx.x;
  const int lane = t & 63;
  const int w = t >> 6;  // 0..15
  const int l15 = lane & 15, l4 = lane >> 4;

  // 160KB LDS: lkp 64KB | lvpt 64KB | lp 32KB (16 waves x 2KB)
  __shared__ __align__(16) short lbuf[81920];
  short* lkp = lbuf;
  short* lvpt = lbuf + 32768;
  short* lpw = lbuf + 65536 + w * 1024;  // 2KB/wave: 16 rows x 128B

  const short* __restrict__ kpb = kp + (size_t)b * 32768;
  const short* __restrict__ vptb = vpt + (size_t)b * 32768;

  // ---- stage kp + vpt (linear LDS dest, swizzled source) ----
#pragma unroll
  for (int i = 0; i < 4; ++i) {
    int g = t + i * 1024;
    int row = g >> 4, c = g & 15;
    __builtin_amdgcn_global_load_lds(
        (const __attribute__((address_space(1))) void*)(kpb + (size_t)row * 128 +
                                                        ((c ^ (row & 7)) << 3)),
        (__attribute__((address_space(3))) void*)(&lkp[g * 8]), 16, 0, 0);
  }
#pragma unroll
  for (int i = 0; i < 4; ++i) {
    int g = t + i * 1024;
    int row = g >> 5, c = g & 31;
    __builtin_amdgcn_global_load_lds(
        (const __attribute__((address_space(1))) void*)(vptb + (size_t)row * 256 +
                                                        ((c ^ (row & 7)) << 3)),
        (__attribute__((address_space(3))) void*)(&lvpt[g * 8]), 16, 0, 0);
  }

  const float scale = 0.08838834764831845f;  // 1/sqrt(128)
  f32x4 qraw[8];
  {
    const float* qr = Q + ((size_t)b * N_SEQ + slice * 512 + w * 16 + l15) * D_HEAD;
#pragma unroll
    for (int ks = 0; ks < 4; ++ks) {
      qraw[2 * ks] = *(const f32x4*)(qr + ks * 32 + l4 * 8);
      qraw[2 * ks + 1] = *(const f32x4*)(qr + ks * 32 + l4 * 8 + 4);
    }
  }
  asm volatile("s_waitcnt vmcnt(0)" ::: "memory");
  __syncthreads();

#pragma unroll
  for (int rd = 0; rd < 2; ++rd) {
    const int rowBase = slice * 512 + rd * 256 + w * 16;

    bf16x8 qf[4];
#pragma unroll
    for (int ks = 0; ks < 4; ++ks) {
      union { unsigned int u[4]; bf16x8 v; } cv;
      cv.u[0] = cvtpk(qraw[2 * ks][0] * scale, qraw[2 * ks][1] * scale);
      cv.u[1] = cvtpk(qraw[2 * ks][2] * scale, qraw[2 * ks][3] * scale);
      cv.u[2] = cvtpk(qraw[2 * ks + 1][0] * scale, qraw[2 * ks + 1][1] * scale);
      cv.u[3] = cvtpk(qraw[2 * ks + 1][2] * scale, qraw[2 * ks + 1][3] * scale);
      qf[ks] = cv.v;
    }

    f32x4 accs[16];
#pragma unroll
    for (int i = 0; i < 16; ++i) accs[i] = (f32x4){0.f, 0.f, 0.f, 0.f};
#pragma unroll
    for (int ks = 0; ks < 4; ++ks) {
#pragma unroll
      for (int nt = 0; nt < 16; ++nt) {
        bf16x8 af = *(const bf16x8*)(&lkp[(nt * 16 + l15) * 128 +
                                          (((ks * 4 + l4) ^ (l15 & 7)) << 3)]);
        accs[nt] = __builtin_amdgcn_mfma_f32_16x16x32_bf16(af, qf[ks], accs[nt], 0, 0, 0);
      }
    }

    float m = -1e30f;
#pragma unroll
    for (int nt = 0; nt < 16; ++nt)
#pragma unroll
      for (int r = 0; r < 4; ++r) m = fmaxf(m, accs[nt][r]);
    m = fmaxf(m, __shfl_xor(m, 16));
    m = fmaxf(m, __shfl_xor(m, 32));
    float s = 0.f;
#pragma unroll
    for (int nt = 0; nt < 16; ++nt)
#pragma unroll
      for (int r = 0; r < 4; ++r) {
        float e = __expf(accs[nt][r] - m);
        accs[nt][r] = e;
        s += e;
      }
    s += __shfl_xor(s, 16);
    s += __shfl_xor(s, 32);
    float inv = 1.0f / s;

    f32x4 acco[8];
#pragma unroll
    for (int i = 0; i < 8; ++i) acco[i] = (f32x4){0.f, 0.f, 0.f, 0.f};
#pragma unroll
    for (int qq = 0; qq < 4; ++qq) {
#pragma unroll
      for (int ntl = 0; ntl < 4; ++ntl) {
        int nt = qq * 4 + ntl;
        int cw = 2 * ntl + (l4 >> 1);
        unsigned int p0 = cvtpk(accs[nt][0] * inv, accs[nt][1] * inv);
        unsigned int p1 = cvtpk(accs[nt][2] * inv, accs[nt][3] * inv);
        *(u32x2*)((char*)lpw + l15 * 128 + ((cw ^ (l15 & 7)) << 4) + (l4 & 1) * 8) =
            (u32x2){p0, p1};
      }
      if (rd == 0 && qq == 3) {
        const float* qr = Q + ((size_t)b * N_SEQ + slice * 512 + 256 + w * 16 + l15) * D_HEAD;
#pragma unroll
        for (int ks = 0; ks < 4; ++ks) {
          qraw[2 * ks] = *(const f32x4*)(qr + ks * 32 + l4 * 8);
          qraw[2 * ks + 1] = *(const f32x4*)(qr + ks * 32 + l4 * 8 + 4);
        }
      }
#pragma unroll
      for (int ksl = 0; ksl < 2; ++ksl) {
        bf16x8 pa = *(const bf16x8*)((char*)lpw + l15 * 128 +
                                     (((4 * ksl + l4) ^ (l15 & 7)) << 4));
        int ksa = qq * 2 + ksl;
#pragma unroll
        for (int ntv = 0; ntv < 8; ++ntv) {
          bf16x8 av = *(const bf16x8*)(&lvpt[(ntv * 16 + l15) * 256 +
                                             (((ksa * 4 + l4) ^ (l15 & 7)) << 3)]);
          acco[ntv] = __builtin_amdgcn_mfma_f32_16x16x32_bf16(av, pa, acco[ntv], 0, 0, 0);
        }
      }
    }

    float* ob = out + ((size_t)b * N_SEQ + rowBase) * D_HEAD;
#pragma unroll
    for (int ntv = 0; ntv < 8; ++ntv)
      *(f32x4*)(ob + (size_t)l15 * D_HEAD + ntv * 16 + l4 * 4) = acco[ntv];
  }
}

// ---------------------------------------------------------------------------
extern "C" void kernel_launch(void* const* d_in, const int* in_sizes, int n_in,
                              void* d_out, int out_size, void* d_ws, size_t ws_size,
                              hipStream_t stream) {
  const float* Q  = (const float*)d_in[0];
  const float* K  = (const float*)d_in[1];
  const float* V  = (const float*)d_in[2];
  const float* EW = (const float*)d_in[3];
  const float* Eb = (const float*)d_in[4];
  const float* FW = (const float*)d_in[5];
  const float* Fb = (const float*)d_in[6];
  float* out = (float*)d_out;

  // d_out scratch: [0,4MB) wbf bf16 W (dead before attn writes out)
  short* wbf = (short*)d_out;
  short* kpb = (short*)d_ws;
  short* vpt = (short*)((char*)d_ws + (size_t)32 * KP_DIM * D_HEAD * 2);

  conv_w_kernel<<<dim3(2048), dim3(256), 0, stream>>>(EW, FW, wbf);
  proj_full_kernel<<<dim3(512), dim3(256), 0, stream>>>(K, V, wbf, Eb, Fb, kpb, vpt);
  attn_kernel<<<dim3(256), dim3(1024), 0, stream>>>(Q, kpb, vpt, out);
}